// Round 10
// baseline (106.698 us; speedup 1.0000x reference)
//
#include <hip/hip_runtime.h>

#define N_PTS 32768
#define M_Q   8192
#define C_F   256
#define PS    4                  // point-range splits
#define RNG   (N_PTS / PS)       // 8192 points per range
#define QW    8                  // queries per wave
#define NW    4                  // waves per block
#define QBL   (QW * NW)          // 32 queries per block
#define NSL   2                  // slots per range (4096 pts each)
#define NQB   (M_Q / QBL)        // 256 query blocks per side
#define MU    1e-3f              // rigorous e-vs-(d*-a2) pruning margin

__device__ __forceinline__ float rn_mul(float a, float b) { return __fmul_rn(a, b); }
__device__ __forceinline__ float rn_add(float a, float b) { return __fadd_rn(a, b); }
__device__ __forceinline__ float rfl(float x) {
    return __int_as_float(__builtin_amdgcn_readfirstlane(__float_as_int(x)));
}

// exact lexicographic (d,i) insert into running top-2 pair
__device__ __forceinline__ void ins_lex(float d, int i, float& b1, int& j1,
                                        float& b2, int& j2) {
    bool lt1 = (d < b1) || (d == b1 && i < j1);
    bool lt2 = (d < b2) || (d == b2 && i < j2);
    b2 = lt1 ? b1 : (lt2 ? d : b2);
    j2 = lt1 ? j1 : (lt2 ? i : j2);
    b1 = lt1 ? d : b1;
    j1 = lt1 ? i : j1;
}

// reduced insert: caller guarantees (d,i) >=lex running b1 (sorted-pair merge)
__device__ __forceinline__ void ins_lex2(float d, int i, float& b2, int& j2) {
    bool lt2 = (d < b2) || (d == b2 && i < j2);
    b2 = lt2 ? d : b2;
    j2 = lt2 ? i : j2;
}

// merge two value-pairs (each a1<=a2) -> two smallest overall
__device__ __forceinline__ void vpair_merge(float& a1, float& a2, float b1, float b2) {
    float n1 = fminf(a1, b1);
    float n2 = fminf(fmaxf(a1, b1), fminf(a2, b2));
    a1 = n1; a2 = n2;
}

// Pack [-2x, -2y, -2z, b2] per point; b2 exact numpy (x*x + y*y) + z*z.
__global__ __launch_bounds__(256) void pack_pts(const float* __restrict__ c0,
                                                const float* __restrict__ c1,
                                                float4* __restrict__ pts) {
    int t = blockIdx.x * blockDim.x + threadIdx.x;   // 0 .. 2N-1
    int side = t >> 15;
    int n = t & (N_PTS - 1);
    const float* c = side ? c1 : c0;
    float x = c[n * 3 + 0], y = c[n * 3 + 1], z = c[n * 3 + 2];
    float b2 = rn_add(rn_add(rn_mul(x, x), rn_mul(y, y)), rn_mul(z, z));
    pts[t] = make_float4(-2.0f * x, -2.0f * y, -2.0f * z, b2);  // *2 exact
}

// Pass 1: branchless e-space chunk minima, 2 pts/iter, min3 fusion.
// Pass 2: exact-numpy rescan of surviving 64-pt chunks, lex top-2.
__global__ __launch_bounds__(256) void pool_scan(
    const float* __restrict__ sc0, const float* __restrict__ sc1,
    const float4* __restrict__ pts, int4* __restrict__ part)
{
    int bid  = blockIdx.x;            // 2 * NQB * PS = 2048
    int side = bid >> 10;
    int r    = bid & 1023;
    int qblk = r >> 2;                // 0..255
    int ps   = r & (PS - 1);          // 0..3
    const float* sc = side ? sc1 : sc0;

    int tid  = threadIdx.x;
    int wave = tid >> 6;
    int lane = tid & 63;
    int q0   = qblk * QBL + wave * QW;              // query base (within side)
    const float4* Pg = pts + (size_t)side * N_PTS + ps * RNG;

    // wave-uniform raw query scalars (SGPR) + exact numpy a2
    float ax[QW], ay[QW], az[QW], a2[QW];
#pragma unroll
    for (int q = 0; q < QW; ++q) {
        int qq = q0 + q;
        float x = rfl(sc[qq * 3 + 0]);
        float y = rfl(sc[qq * 3 + 1]);
        float z = rfl(sc[qq * 3 + 2]);
        ax[q] = x; ay[q] = y; az[q] = z;
        a2[q] = rfl(rn_add(rn_add(rn_mul(x, x), rn_mul(y, y)), rn_mul(z, z)));
    }

    float m[NSL][QW];
#pragma unroll
    for (int s = 0; s < NSL; ++s)
#pragma unroll
        for (int q = 0; q < QW; ++q) m[s][q] = __int_as_float(0x7f800000);

    // ---- Pass 1: 2 coalesced pts/iter; barrier every 8 iters (16 KB = L1
    //      window) so the block's 4 waves convoy and followers hit L1 ----
#pragma unroll
    for (int s = 0; s < NSL; ++s) {
        for (int w = 0; w < 4; ++w) {             // 4 windows of 8 iters
#pragma unroll
            for (int j = 0; j < 8; ++j) {
                const float4* bp = Pg + s * 4096 + (w * 8 + j) * 128;
                float4 p0 = bp[lane];
                float4 p1 = bp[64 + lane];
#pragma unroll
                for (int q = 0; q < QW; ++q) {
                    // e = b2 - 2*dot (premultiplied points): 3 FMA each
                    float e0 = __builtin_fmaf(az[q], p0.z,
                                __builtin_fmaf(ay[q], p0.y,
                                 __builtin_fmaf(ax[q], p0.x, p0.w)));
                    float e1 = __builtin_fmaf(az[q], p1.z,
                                __builtin_fmaf(ay[q], p1.y,
                                 __builtin_fmaf(ax[q], p1.x, p1.w)));
                    m[s][q] = fminf(m[s][q], fminf(e0, e1));  // v_min3
                }
            }
            __syncthreads();
        }
    }

    // ---- beta per query: 2nd-smallest lane-chunk min over this range ----
    float beta[QW];
#pragma unroll
    for (int q = 0; q < QW; ++q) {
        float p1 = fminf(m[0][q], m[1][q]);
        float p2 = fmaxf(m[0][q], m[1][q]);
#pragma unroll
        for (int off = 1; off < 64; off <<= 1) {
            float o1 = __shfl_xor(p1, off);
            float o2 = __shfl_xor(p2, off);
            vpair_merge(p1, p2, o1, o2);
        }
        beta[q] = rfl(p2) + MU;
    }

    // ---- Pass 2: exact rescan of surviving 64-pt chunks ----
    float D1[QW], D2[QW];
    int   I1[QW], I2[QW];
#pragma unroll
    for (int q = 0; q < QW; ++q) {
        D1[q] = __int_as_float(0x7f800000); D2[q] = D1[q];
        I1[q] = 0x7fffffff; I2[q] = 0x7fffffff;
    }
    int jj = lane >> 1, hh = lane & 1;   // rescan: lane -> (iter, half) of chunk
#pragma unroll
    for (int s = 0; s < NSL; ++s) {
#pragma unroll
        for (int q = 0; q < QW; ++q) {
            unsigned long long fm = __ballot(m[s][q] <= beta[q]);
            while (fm) {                       // ~2 fires per query
                int lf = (int)__builtin_ctzll(fm);
                fm &= fm - 1;
                int rel = s * 4096 + jj * 128 + hh * 64 + lf;
                float4 p = Pg[rel];
                float x = -0.5f * p.x, y = -0.5f * p.y, z = -0.5f * p.z; // exact
                float dot = __builtin_fmaf(az[q], z,
                             __builtin_fmaf(ay[q], y, rn_mul(ax[q], x)));
                float dd = __builtin_fmaf(-2.0f, dot, rn_add(a2[q], p.w));
                ins_lex(dd, ps * RNG + rel, D1[q], I1[q], D2[q], I2[q]);
            }
        }
    }

    // butterfly lex-merge across 64 lanes (sorted-pair: 2nd insert reduced)
#pragma unroll
    for (int off = 1; off < 64; off <<= 1) {
#pragma unroll
        for (int q = 0; q < QW; ++q) {
            float od1 = __shfl_xor(D1[q], off); int oi1 = __shfl_xor(I1[q], off);
            float od2 = __shfl_xor(D2[q], off); int oi2 = __shfl_xor(I2[q], off);
            ins_lex(od1, oi1, D1[q], I1[q], D2[q], I2[q]);
            ins_lex2(od2, oi2, D2[q], I2[q]);
        }
    }
    if (lane == 0) {
#pragma unroll
        for (int q = 0; q < QW; ++q) {
            int qg = side * M_Q + q0 + q;
            part[qg * PS + ps] = make_int4(__float_as_int(D1[q]), I1[q],
                                           __float_as_int(D2[q]), I2[q]);
        }
    }
}

// Merge the PS partials per query (exact lex), gather feature rows.
__global__ __launch_bounds__(256) void merge_gather(
    const float* __restrict__ src, const float* __restrict__ tgt,
    const int4* __restrict__ part, float* __restrict__ out)
{
    __shared__ int sidx[8];

    int bid  = blockIdx.x;            // 2 * M_Q/8 = 2048
    int side = bid >> 10;
    int qb   = bid & 1023;
    const float* feats = side ? tgt : src;
    int tid = threadIdx.x;
    int q0  = qb * 8;

    if (tid < 8) {
        int qg = side * M_Q + q0 + tid;
        int4 p0 = part[qg * PS + 0];
        float b1 = __int_as_float(p0.x), b2 = __int_as_float(p0.z);
        int   j1 = p0.y,                 j2 = p0.w;
#pragma unroll
        for (int sp = 1; sp < PS; ++sp) {
            int4 p = part[qg * PS + sp];
            ins_lex(__int_as_float(p.x), p.y, b1, j1, b2, j2);
            ins_lex2(__int_as_float(p.z), p.w, b2, j2);
        }
        sidx[tid] = j2;
    }
    __syncthreads();

    // gather: 8 rows of 256 floats; 32 threads per row, 2 float4 each
    int qi = tid >> 5;
    int cj = tid & 31;
    int row = sidx[qi];
    const float4* sp = (const float4*)(feats + (size_t)row * C_F);
    float4* dp = (float4*)(out + ((size_t)side * M_Q + q0 + qi) * (size_t)C_F);
    dp[cj]      = sp[cj];
    dp[cj + 32] = sp[cj + 32];
}

extern "C" void kernel_launch(void* const* d_in, const int* in_sizes, int n_in,
                              void* d_out, int out_size, void* d_ws, size_t ws_size,
                              hipStream_t stream) {
    const float* src  = (const float*)d_in[0];
    const float* tgt  = (const float*)d_in[1];
    const float* c0   = (const float*)d_in[2];  // src_coords   (N,3)
    const float* c1   = (const float*)d_in[3];  // tgt_coords   (N,3)
    const float* sh0  = (const float*)d_in[4];  // src_shortcut (M,3)
    const float* sh1  = (const float*)d_in[5];  // tgt_shortcut (M,3)
    float* out = (float*)d_out;

    float4* pts  = (float4*)d_ws;                                   // 1 MB
    int4*   part = (int4*)((char*)d_ws + (size_t)2 * N_PTS * sizeof(float4)); // 2 MB

    hipLaunchKernelGGL(pack_pts, dim3(2 * N_PTS / 256), dim3(256), 0, stream,
                       c0, c1, pts);
    hipLaunchKernelGGL(pool_scan, dim3(2 * NQB * PS), dim3(256), 0, stream,
                       sh0, sh1, pts, part);
    hipLaunchKernelGGL(merge_gather, dim3(2 * (M_Q / 8)), dim3(256), 0, stream,
                       src, tgt, part, out);
}

// Round 11
// 96.610 us; speedup vs baseline: 1.1044x; 1.1044x over previous
//
#include <hip/hip_runtime.h>

#define N_PTS 32768
#define M_Q   8192
#define C_F   256
#define PS    4                  // point-range splits
#define RNG   (N_PTS / PS)       // 8192 points per range
#define CH    512                // points per staged LDS chunk (8 KB)
#define NCHK  (RNG / CH)         // 16 chunks per range
#define HCHK  (NCHK / 2)         // 8 chunks per slot
#define QW    8                  // queries per wave
#define NW    4                  // waves per block
#define QBL   (QW * NW)          // 32 queries per block
#define NSL   2                  // pruning slots (each = 8 chunks = 4096 pts)
#define NQB   (M_Q / QBL)        // 256 query blocks per side
#define MU    1e-3f              // rigorous e-vs-(d*-a2) pruning margin

__device__ __forceinline__ float rn_mul(float a, float b) { return __fmul_rn(a, b); }
__device__ __forceinline__ float rn_add(float a, float b) { return __fadd_rn(a, b); }
__device__ __forceinline__ float rfl(float x) {
    return __int_as_float(__builtin_amdgcn_readfirstlane(__float_as_int(x)));
}

// exact lexicographic (d,i) insert into running top-2 pair
__device__ __forceinline__ void ins_lex(float d, int i, float& b1, int& j1,
                                        float& b2, int& j2) {
    bool lt1 = (d < b1) || (d == b1 && i < j1);
    bool lt2 = (d < b2) || (d == b2 && i < j2);
    b2 = lt1 ? b1 : (lt2 ? d : b2);
    j2 = lt1 ? j1 : (lt2 ? i : j2);
    b1 = lt1 ? d : b1;
    j1 = lt1 ? i : j1;
}

// reduced insert: caller guarantees (d,i) >=lex running b1 (sorted-pair merge)
__device__ __forceinline__ void ins_lex2(float d, int i, float& b2, int& j2) {
    bool lt2 = (d < b2) || (d == b2 && i < j2);
    b2 = lt2 ? d : b2;
    j2 = lt2 ? i : j2;
}

// merge two value-pairs (each a1<=a2) -> two smallest overall
__device__ __forceinline__ void vpair_merge(float& a1, float& a2, float b1, float b2) {
    float n1 = fminf(a1, b1);
    float n2 = fminf(fmaxf(a1, b1), fminf(a2, b2));
    a1 = n1; a2 = n2;
}

// Pack [-2x, -2y, -2z, b2] per point; b2 exact numpy (x*x + y*y) + z*z.
__global__ __launch_bounds__(256) void pack_pts(const float* __restrict__ c0,
                                                const float* __restrict__ c1,
                                                float4* __restrict__ pts) {
    int t = blockIdx.x * blockDim.x + threadIdx.x;   // 0 .. 2N-1
    int side = t >> 15;
    int n = t & (N_PTS - 1);
    const float* c = side ? c1 : c0;
    float x = c[n * 3 + 0], y = c[n * 3 + 1], z = c[n * 3 + 2];
    float b2 = rn_add(rn_add(rn_mul(x, x), rn_mul(y, y)), rn_mul(z, z));
    pts[t] = make_float4(-2.0f * x, -2.0f * y, -2.0f * z, b2);  // *2 exact
}

// Pass 1: LDS-staged (double-buffered) branchless e-space chunk minima.
// Pass 2: exact-numpy rescan of surviving 64-pt lane-chunks, lex top-2.
__global__ __launch_bounds__(256, 6) void pool_scan(
    const float* __restrict__ sc0, const float* __restrict__ sc1,
    const float4* __restrict__ pts, int4* __restrict__ part)
{
    __shared__ float4 buf[2][CH];     // 16 KB double buffer

    int bid  = blockIdx.x;            // 2 * NQB * PS = 2048
    int side = bid >> 10;
    int r    = bid & 1023;
    int qblk = r >> 2;                // 0..255
    int ps   = r & (PS - 1);          // 0..3
    const float* sc = side ? sc1 : sc0;

    int tid  = threadIdx.x;
    int wave = tid >> 6;
    int lane = tid & 63;
    int q0   = qblk * QBL + wave * QW;              // query base (within side)
    const float4* Pg = pts + (size_t)side * N_PTS + ps * RNG;

    // wave-uniform raw query scalars (SGPR) + exact numpy a2
    float ax[QW], ay[QW], az[QW], a2[QW];
#pragma unroll
    for (int q = 0; q < QW; ++q) {
        int qq = q0 + q;
        float x = rfl(sc[qq * 3 + 0]);
        float y = rfl(sc[qq * 3 + 1]);
        float z = rfl(sc[qq * 3 + 2]);
        ax[q] = x; ay[q] = y; az[q] = z;
        a2[q] = rfl(rn_add(rn_add(rn_mul(x, x), rn_mul(y, y)), rn_mul(z, z)));
    }

    float m[NSL][QW];
#pragma unroll
    for (int s = 0; s < NSL; ++s)
#pragma unroll
        for (int q = 0; q < QW; ++q) m[s][q] = __int_as_float(0x7f800000);

    // stage chunk 0 (each thread: 2 float4)
    buf[0][tid]       = Pg[tid];
    buf[0][256 + tid] = Pg[256 + tid];
    __syncthreads();

    // ---- Pass 1: 16-chunk double-buffered convoy scan ----
#pragma unroll
    for (int s = 0; s < NSL; ++s) {                 // static slot index for m[]
        for (int cc = 0; cc < HCHK; ++cc) {         // 8 chunks per slot
            int c = s * HCHK + cc;
            float4 st0, st1;
            bool pf = (c + 1 < NCHK);
            if (pf) {                               // issue next-chunk loads early
                st0 = Pg[(c + 1) * CH + tid];
                st1 = Pg[(c + 1) * CH + 256 + tid];
            }
            const float4* cb = buf[c & 1];
#pragma unroll
            for (int j = 0; j < 4; ++j) {           // 8 pts per lane, paired
                float4 p0 = cb[(2 * j) * 64 + lane];
                float4 p1 = cb[(2 * j + 1) * 64 + lane];
#pragma unroll
                for (int q = 0; q < QW; ++q) {
                    // e = b2 - 2*dot (premultiplied points): 3 FMA each
                    float e0 = __builtin_fmaf(az[q], p0.z,
                                __builtin_fmaf(ay[q], p0.y,
                                 __builtin_fmaf(ax[q], p0.x, p0.w)));
                    float e1 = __builtin_fmaf(az[q], p1.z,
                                __builtin_fmaf(ay[q], p1.y,
                                 __builtin_fmaf(ax[q], p1.x, p1.w)));
                    m[s][q] = fminf(m[s][q], fminf(e0, e1));  // v_min3
                }
            }
            if (pf) {                               // write-late into other buffer
                float4* nb = buf[(c + 1) & 1];
                nb[tid]       = st0;
                nb[256 + tid] = st1;
            }
            __syncthreads();
        }
    }

    // ---- beta per query: 2nd-smallest lane-chunk min over this range ----
    float beta[QW];
#pragma unroll
    for (int q = 0; q < QW; ++q) {
        float p1 = fminf(m[0][q], m[1][q]);
        float p2 = fmaxf(m[0][q], m[1][q]);
#pragma unroll
        for (int off = 1; off < 64; off <<= 1) {
            float o1 = __shfl_xor(p1, off);
            float o2 = __shfl_xor(p2, off);
            vpair_merge(p1, p2, o1, o2);
        }
        beta[q] = rfl(p2) + MU;
    }

    // ---- Pass 2: exact rescan of surviving 64-pt lane-chunks ----
    float D1[QW], D2[QW];
    int   I1[QW], I2[QW];
#pragma unroll
    for (int q = 0; q < QW; ++q) {
        D1[q] = __int_as_float(0x7f800000); D2[q] = D1[q];
        I1[q] = 0x7fffffff; I2[q] = 0x7fffffff;
    }
    int cc2 = lane >> 3, j2 = lane & 7;  // rescan: lane -> (chunk, j) in slot
#pragma unroll
    for (int s = 0; s < NSL; ++s) {
#pragma unroll
        for (int q = 0; q < QW; ++q) {
            unsigned long long fm = __ballot(m[s][q] <= beta[q]);
            while (fm) {                       // ~2-3 fires per query
                int l = (int)__builtin_ctzll(fm);
                fm &= fm - 1;
                int rel = (s * HCHK + cc2) * CH + j2 * 64 + l;
                float4 p = Pg[rel];
                float x = -0.5f * p.x, y = -0.5f * p.y, z = -0.5f * p.z; // exact
                float dot = __builtin_fmaf(az[q], z,
                             __builtin_fmaf(ay[q], y, rn_mul(ax[q], x)));
                float dd = __builtin_fmaf(-2.0f, dot, rn_add(a2[q], p.w));
                ins_lex(dd, ps * RNG + rel, D1[q], I1[q], D2[q], I2[q]);
            }
        }
    }

    // butterfly lex-merge across 64 lanes (sorted-pair: 2nd insert reduced)
#pragma unroll
    for (int off = 1; off < 64; off <<= 1) {
#pragma unroll
        for (int q = 0; q < QW; ++q) {
            float od1 = __shfl_xor(D1[q], off); int oi1 = __shfl_xor(I1[q], off);
            float od2 = __shfl_xor(D2[q], off); int oi2 = __shfl_xor(I2[q], off);
            ins_lex(od1, oi1, D1[q], I1[q], D2[q], I2[q]);
            ins_lex2(od2, oi2, D2[q], I2[q]);
        }
    }
    if (lane == 0) {
#pragma unroll
        for (int q = 0; q < QW; ++q) {
            int qg = side * M_Q + q0 + q;
            part[qg * PS + ps] = make_int4(__float_as_int(D1[q]), I1[q],
                                           __float_as_int(D2[q]), I2[q]);
        }
    }
}

// Merge the PS partials per query (exact lex), gather feature rows.
__global__ __launch_bounds__(256) void merge_gather(
    const float* __restrict__ src, const float* __restrict__ tgt,
    const int4* __restrict__ part, float* __restrict__ out)
{
    __shared__ int sidx[8];

    int bid  = blockIdx.x;            // 2 * M_Q/8 = 2048
    int side = bid >> 10;
    int qb   = bid & 1023;
    const float* feats = side ? tgt : src;
    int tid = threadIdx.x;
    int q0  = qb * 8;

    if (tid < 8) {
        int qg = side * M_Q + q0 + tid;
        int4 p0 = part[qg * PS + 0];
        float b1 = __int_as_float(p0.x), b2 = __int_as_float(p0.z);
        int   j1 = p0.y,                 j2 = p0.w;
#pragma unroll
        for (int sp = 1; sp < PS; ++sp) {
            int4 p = part[qg * PS + sp];
            ins_lex(__int_as_float(p.x), p.y, b1, j1, b2, j2);
            ins_lex2(__int_as_float(p.z), p.w, b2, j2);
        }
        sidx[tid] = j2;
    }
    __syncthreads();

    // gather: 8 rows of 256 floats; 32 threads per row, 2 float4 each
    int qi = tid >> 5;
    int cj = tid & 31;
    int row = sidx[qi];
    const float4* sp = (const float4*)(feats + (size_t)row * C_F);
    float4* dp = (float4*)(out + ((size_t)side * M_Q + q0 + qi) * (size_t)C_F);
    dp[cj]      = sp[cj];
    dp[cj + 32] = sp[cj + 32];
}

extern "C" void kernel_launch(void* const* d_in, const int* in_sizes, int n_in,
                              void* d_out, int out_size, void* d_ws, size_t ws_size,
                              hipStream_t stream) {
    const float* src  = (const float*)d_in[0];
    const float* tgt  = (const float*)d_in[1];
    const float* c0   = (const float*)d_in[2];  // src_coords   (N,3)
    const float* c1   = (const float*)d_in[3];  // tgt_coords   (N,3)
    const float* sh0  = (const float*)d_in[4];  // src_shortcut (M,3)
    const float* sh1  = (const float*)d_in[5];  // tgt_shortcut (M,3)
    float* out = (float*)d_out;

    float4* pts  = (float4*)d_ws;                                   // 1 MB
    int4*   part = (int4*)((char*)d_ws + (size_t)2 * N_PTS * sizeof(float4)); // 2 MB

    hipLaunchKernelGGL(pack_pts, dim3(2 * N_PTS / 256), dim3(256), 0, stream,
                       c0, c1, pts);
    hipLaunchKernelGGL(pool_scan, dim3(2 * NQB * PS), dim3(256), 0, stream,
                       sh0, sh1, pts, part);
    hipLaunchKernelGGL(merge_gather, dim3(2 * (M_Q / 8)), dim3(256), 0, stream,
                       src, tgt, part, out);
}

// Round 12
// 95.349 us; speedup vs baseline: 1.1190x; 1.0132x over previous
//
#include <hip/hip_runtime.h>

#define N_PTS 32768
#define M_Q   8192
#define C_F   256
#define PS    4                  // point-range splits
#define RNG   (N_PTS / PS)       // 8192 points per range
#define CH    512                // points per staged LDS chunk (8 KB)
#define NCHK  (RNG / CH)         // 16 chunks per range
#define HCHK  (NCHK / 2)         // 8 chunks per slot
#define QW    8                  // queries per wave
#define NW    4                  // waves per block
#define QBL   (QW * NW)          // 32 queries per block
#define NSL   2                  // pruning slots (each = 8 chunks = 4096 pts)
#define NQB   (M_Q / QBL)        // 256 query blocks per side
#define MU    1e-3f              // rigorous e-vs-(d*-a2) pruning margin

__device__ __forceinline__ float rn_mul(float a, float b) { return __fmul_rn(a, b); }
__device__ __forceinline__ float rn_add(float a, float b) { return __fadd_rn(a, b); }
__device__ __forceinline__ float rfl(float x) {
    return __int_as_float(__builtin_amdgcn_readfirstlane(__float_as_int(x)));
}

// ---- cross-lane primitives on the VALU pipe (DPP) + 1 swizzle + readlane ----
template<int CTRL>
__device__ __forceinline__ float dppf(float v) {
    return __int_as_float(__builtin_amdgcn_update_dpp(
        __float_as_int(v), __float_as_int(v), CTRL, 0xF, 0xF, false));
}
template<int CTRL>
__device__ __forceinline__ int dppi(int v) {
    return __builtin_amdgcn_update_dpp(v, v, CTRL, 0xF, 0xF, false);
}
__device__ __forceinline__ float swz16f(float v) {   // lane ^= 16 (LDS pipe, 1 op)
    return __int_as_float(__builtin_amdgcn_ds_swizzle(__float_as_int(v), 0x401F));
}
__device__ __forceinline__ int swz16i(int v) {
    return __builtin_amdgcn_ds_swizzle(v, 0x401F);
}
__device__ __forceinline__ float rlf(float v, int l) {
    return __int_as_float(__builtin_amdgcn_readlane(__float_as_int(v), l));
}
__device__ __forceinline__ int rli(int v, int l) {
    return __builtin_amdgcn_readlane(v, l);
}

// exact lexicographic (d,i) insert into running top-2 pair
__device__ __forceinline__ void ins_lex(float d, int i, float& b1, int& j1,
                                        float& b2, int& j2) {
    bool lt1 = (d < b1) || (d == b1 && i < j1);
    bool lt2 = (d < b2) || (d == b2 && i < j2);
    b2 = lt1 ? b1 : (lt2 ? d : b2);
    j2 = lt1 ? j1 : (lt2 ? i : j2);
    b1 = lt1 ? d : b1;
    j1 = lt1 ? i : j1;
}

// reduced insert: caller guarantees (d,i) >=lex running b1 (sorted-pair merge)
__device__ __forceinline__ void ins_lex2(float d, int i, float& b2, int& j2) {
    bool lt2 = (d < b2) || (d == b2 && i < j2);
    b2 = lt2 ? d : b2;
    j2 = lt2 ? i : j2;
}

// merge two value-pairs (each a1<=a2) -> two smallest overall
__device__ __forceinline__ void vpair_merge(float& a1, float& a2, float b1, float b2) {
    float n1 = fminf(a1, b1);
    float n2 = fminf(fmaxf(a1, b1), fminf(a2, b2));
    a1 = n1; a2 = n2;
}

// Pack [-2x, -2y, -2z, b2] per point; b2 exact numpy (x*x + y*y) + z*z.
__global__ __launch_bounds__(256) void pack_pts(const float* __restrict__ c0,
                                                const float* __restrict__ c1,
                                                float4* __restrict__ pts) {
    int t = blockIdx.x * blockDim.x + threadIdx.x;   // 0 .. 2N-1
    int side = t >> 15;
    int n = t & (N_PTS - 1);
    const float* c = side ? c1 : c0;
    float x = c[n * 3 + 0], y = c[n * 3 + 1], z = c[n * 3 + 2];
    float b2 = rn_add(rn_add(rn_mul(x, x), rn_mul(y, y)), rn_mul(z, z));
    pts[t] = make_float4(-2.0f * x, -2.0f * y, -2.0f * z, b2);  // *2 exact
}

// Pass 1: LDS-staged branchless e-space chunk minima.
// Reductions: DPP doubling rotations (VALU) + 1 xor16 swizzle + readlane.
// Pass 2: exact-numpy rescan of surviving 64-pt lane-chunks, lex top-2.
__global__ __launch_bounds__(256, 6) void pool_scan(
    const float* __restrict__ sc0, const float* __restrict__ sc1,
    const float4* __restrict__ pts, int4* __restrict__ part)
{
    __shared__ float4 buf[2][CH];     // 16 KB double buffer

    int bid  = blockIdx.x;            // 2 * NQB * PS = 2048
    int side = bid >> 10;
    int r    = bid & 1023;
    int qblk = r >> 2;                // 0..255
    int ps   = r & (PS - 1);          // 0..3
    const float* sc = side ? sc1 : sc0;

    int tid  = threadIdx.x;
    int wave = tid >> 6;
    int lane = tid & 63;
    int q0   = qblk * QBL + wave * QW;              // query base (within side)
    const float4* Pg = pts + (size_t)side * N_PTS + ps * RNG;

    // wave-uniform raw query scalars (SGPR) + exact numpy a2
    float ax[QW], ay[QW], az[QW], a2[QW];
#pragma unroll
    for (int q = 0; q < QW; ++q) {
        int qq = q0 + q;
        float x = rfl(sc[qq * 3 + 0]);
        float y = rfl(sc[qq * 3 + 1]);
        float z = rfl(sc[qq * 3 + 2]);
        ax[q] = x; ay[q] = y; az[q] = z;
        a2[q] = rfl(rn_add(rn_add(rn_mul(x, x), rn_mul(y, y)), rn_mul(z, z)));
    }

    float m[NSL][QW];
#pragma unroll
    for (int s = 0; s < NSL; ++s)
#pragma unroll
        for (int q = 0; q < QW; ++q) m[s][q] = __int_as_float(0x7f800000);

    // stage chunk 0 (each thread: 2 float4)
    buf[0][tid]       = Pg[tid];
    buf[0][256 + tid] = Pg[256 + tid];
    __syncthreads();

    // ---- Pass 1: 16-chunk double-buffered convoy scan ----
#pragma unroll
    for (int s = 0; s < NSL; ++s) {                 // static slot index for m[]
        for (int cc = 0; cc < HCHK; ++cc) {         // 8 chunks per slot
            int c = s * HCHK + cc;
            float4 st0, st1;
            bool pf = (c + 1 < NCHK);
            if (pf) {                               // issue next-chunk loads early
                st0 = Pg[(c + 1) * CH + tid];
                st1 = Pg[(c + 1) * CH + 256 + tid];
            }
            const float4* cb = buf[c & 1];
#pragma unroll
            for (int j = 0; j < 4; ++j) {           // 8 pts per lane, paired
                float4 p0 = cb[(2 * j) * 64 + lane];
                float4 p1 = cb[(2 * j + 1) * 64 + lane];
#pragma unroll
                for (int q = 0; q < QW; ++q) {
                    // e = b2 - 2*dot (premultiplied points): 3 FMA each
                    float e0 = __builtin_fmaf(az[q], p0.z,
                                __builtin_fmaf(ay[q], p0.y,
                                 __builtin_fmaf(ax[q], p0.x, p0.w)));
                    float e1 = __builtin_fmaf(az[q], p1.z,
                                __builtin_fmaf(ay[q], p1.y,
                                 __builtin_fmaf(ax[q], p1.x, p1.w)));
                    m[s][q] = fminf(m[s][q], fminf(e0, e1));  // v_min3
                }
            }
            if (pf) {                               // write-late into other buffer
                float4* nb = buf[(c + 1) & 1];
                nb[tid]       = st0;
                nb[256 + tid] = st1;
            }
            __syncthreads();
        }
    }

    // ---- beta per query: 2nd-smallest lane-chunk min over this range ----
    // DPP doubling rotations within rows of 16 (disjoint sets), then xor16
    // swizzle, then readlane across the 32-halves -> uniform value.
    float beta[QW];
#pragma unroll
    for (int q = 0; q < QW; ++q) {
        float p1 = fminf(m[0][q], m[1][q]);
        float p2 = fmaxf(m[0][q], m[1][q]);
        { float o1 = dppf<0x121>(p1), o2 = dppf<0x121>(p2); vpair_merge(p1, p2, o1, o2); }
        { float o1 = dppf<0x122>(p1), o2 = dppf<0x122>(p2); vpair_merge(p1, p2, o1, o2); }
        { float o1 = dppf<0x124>(p1), o2 = dppf<0x124>(p2); vpair_merge(p1, p2, o1, o2); }
        { float o1 = dppf<0x128>(p1), o2 = dppf<0x128>(p2); vpair_merge(p1, p2, o1, o2); }
        { float o1 = swz16f(p1),      o2 = swz16f(p2);      vpair_merge(p1, p2, o1, o2); }
        float u1 = rlf(p1, 0),  u2 = rlf(p2, 0);
        float w1 = rlf(p1, 32), w2 = rlf(p2, 32);
        beta[q] = fminf(fmaxf(u1, w1), fminf(u2, w2)) + MU;
    }

    // ---- Pass 2: exact rescan of surviving 64-pt lane-chunks ----
    float D1[QW], D2[QW];
    int   I1[QW], I2[QW];
#pragma unroll
    for (int q = 0; q < QW; ++q) {
        D1[q] = __int_as_float(0x7f800000); D2[q] = D1[q];
        I1[q] = 0x7fffffff; I2[q] = 0x7fffffff;
    }
    int cc2 = lane >> 3, j2l = lane & 7;  // rescan: lane -> (chunk, j) in slot
#pragma unroll
    for (int s = 0; s < NSL; ++s) {
#pragma unroll
        for (int q = 0; q < QW; ++q) {
            unsigned long long fm = __ballot(m[s][q] <= beta[q]);
            while (fm) {                       // ~2-3 fires per query
                int l = (int)__builtin_ctzll(fm);
                fm &= fm - 1;
                int rel = (s * HCHK + cc2) * CH + j2l * 64 + l;
                float4 p = Pg[rel];
                float x = -0.5f * p.x, y = -0.5f * p.y, z = -0.5f * p.z; // exact
                float dot = __builtin_fmaf(az[q], z,
                             __builtin_fmaf(ay[q], y, rn_mul(ax[q], x)));
                float dd = __builtin_fmaf(-2.0f, dot, rn_add(a2[q], p.w));
                ins_lex(dd, ps * RNG + rel, D1[q], I1[q], D2[q], I2[q]);
            }
        }
    }

    // ---- top-2 lex reduce across 64 lanes: DPP rotations + xor16 + readlane ----
#pragma unroll
    for (int q = 0; q < QW; ++q) {
        {
            float od1 = dppf<0x121>(D1[q]); int oi1 = dppi<0x121>(I1[q]);
            float od2 = dppf<0x121>(D2[q]); int oi2 = dppi<0x121>(I2[q]);
            ins_lex(od1, oi1, D1[q], I1[q], D2[q], I2[q]);
            ins_lex2(od2, oi2, D2[q], I2[q]);
        }
        {
            float od1 = dppf<0x122>(D1[q]); int oi1 = dppi<0x122>(I1[q]);
            float od2 = dppf<0x122>(D2[q]); int oi2 = dppi<0x122>(I2[q]);
            ins_lex(od1, oi1, D1[q], I1[q], D2[q], I2[q]);
            ins_lex2(od2, oi2, D2[q], I2[q]);
        }
        {
            float od1 = dppf<0x124>(D1[q]); int oi1 = dppi<0x124>(I1[q]);
            float od2 = dppf<0x124>(D2[q]); int oi2 = dppi<0x124>(I2[q]);
            ins_lex(od1, oi1, D1[q], I1[q], D2[q], I2[q]);
            ins_lex2(od2, oi2, D2[q], I2[q]);
        }
        {
            float od1 = dppf<0x128>(D1[q]); int oi1 = dppi<0x128>(I1[q]);
            float od2 = dppf<0x128>(D2[q]); int oi2 = dppi<0x128>(I2[q]);
            ins_lex(od1, oi1, D1[q], I1[q], D2[q], I2[q]);
            ins_lex2(od2, oi2, D2[q], I2[q]);
        }
        {
            float od1 = swz16f(D1[q]); int oi1 = swz16i(I1[q]);
            float od2 = swz16f(D2[q]); int oi2 = swz16i(I2[q]);
            ins_lex(od1, oi1, D1[q], I1[q], D2[q], I2[q]);
            ins_lex2(od2, oi2, D2[q], I2[q]);
        }
        // cross-32 via readlane: both halves uniform -> final merge on all lanes
        float u1 = rlf(D1[q], 0);  int v1 = rli(I1[q], 0);
        float u2 = rlf(D2[q], 0);  int v2 = rli(I2[q], 0);
        float w1 = rlf(D1[q], 32); int x1 = rli(I1[q], 32);
        float w2 = rlf(D2[q], 32); int x2 = rli(I2[q], 32);
        ins_lex(w1, x1, u1, v1, u2, v2);
        ins_lex2(w2, x2, u2, v2);
        if (lane == 0) {
            int qg = side * M_Q + q0 + q;
            part[qg * PS + ps] = make_int4(__float_as_int(u1), v1,
                                           __float_as_int(u2), v2);
        }
    }
}

// Merge the PS partials per query (exact lex), gather feature rows.
__global__ __launch_bounds__(256) void merge_gather(
    const float* __restrict__ src, const float* __restrict__ tgt,
    const int4* __restrict__ part, float* __restrict__ out)
{
    __shared__ int sidx[8];

    int bid  = blockIdx.x;            // 2 * M_Q/8 = 2048
    int side = bid >> 10;
    int qb   = bid & 1023;
    const float* feats = side ? tgt : src;
    int tid = threadIdx.x;
    int q0  = qb * 8;

    if (tid < 8) {
        int qg = side * M_Q + q0 + tid;
        int4 p0 = part[qg * PS + 0];
        float b1 = __int_as_float(p0.x), b2 = __int_as_float(p0.z);
        int   j1 = p0.y,                 j2 = p0.w;
#pragma unroll
        for (int sp = 1; sp < PS; ++sp) {
            int4 p = part[qg * PS + sp];
            ins_lex(__int_as_float(p.x), p.y, b1, j1, b2, j2);
            ins_lex2(__int_as_float(p.z), p.w, b2, j2);
        }
        sidx[tid] = j2;
    }
    __syncthreads();

    // gather: 8 rows of 256 floats; 32 threads per row, 2 float4 each
    int qi = tid >> 5;
    int cj = tid & 31;
    int row = sidx[qi];
    const float4* sp = (const float4*)(feats + (size_t)row * C_F);
    float4* dp = (float4*)(out + ((size_t)side * M_Q + q0 + qi) * (size_t)C_F);
    dp[cj]      = sp[cj];
    dp[cj + 32] = sp[cj + 32];
}

extern "C" void kernel_launch(void* const* d_in, const int* in_sizes, int n_in,
                              void* d_out, int out_size, void* d_ws, size_t ws_size,
                              hipStream_t stream) {
    const float* src  = (const float*)d_in[0];
    const float* tgt  = (const float*)d_in[1];
    const float* c0   = (const float*)d_in[2];  // src_coords   (N,3)
    const float* c1   = (const float*)d_in[3];  // tgt_coords   (N,3)
    const float* sh0  = (const float*)d_in[4];  // src_shortcut (M,3)
    const float* sh1  = (const float*)d_in[5];  // tgt_shortcut (M,3)
    float* out = (float*)d_out;

    float4* pts  = (float4*)d_ws;                                   // 1 MB
    int4*   part = (int4*)((char*)d_ws + (size_t)2 * N_PTS * sizeof(float4)); // 2 MB

    hipLaunchKernelGGL(pack_pts, dim3(2 * N_PTS / 256), dim3(256), 0, stream,
                       c0, c1, pts);
    hipLaunchKernelGGL(pool_scan, dim3(2 * NQB * PS), dim3(256), 0, stream,
                       sh0, sh1, pts, part);
    hipLaunchKernelGGL(merge_gather, dim3(2 * (M_Q / 8)), dim3(256), 0, stream,
                       src, tgt, part, out);
}